// Round 14
// baseline (124.437 us; speedup 1.0000x reference)
//
#include <hip/hip_runtime.h>

// B=8 T=32 N=10 (I=320) DOBJ=2048 V=157(pad192) C=353 DEMB=512 DVERB=2048
// G-first dataflow (verified round 8), on round-12 verified skeletons:
//  K0 k_cls  : cls[b,i] last-nonzero                       [640]
//  K1 k_prep : featT bf16 || Wt || ctx || sAT || cnt       [6256]
//  K2 k_gemmG: G[b](192x2048) = sAT[b] @ featT[b]  K=320   [384]
//  K3 k_gemm2: part[ks] = G @ Wt  split-K=4, K=512/ks      [384]
//  K4 k_fin  : out[:,:512] = sum_ks part + cnt*bias ; ctx bcast [3280]

typedef __attribute__((ext_vector_type(8))) short short8;
typedef __attribute__((ext_vector_type(8))) unsigned short us8;
typedef __attribute__((ext_vector_type(4))) unsigned short us4;
typedef __attribute__((ext_vector_type(4))) float f32x4;

// workspace (bytes)
#define OFF_CTX  0           // f32[8*2048]            -> 65536
#define OFF_SAT  65536       // bf16[8*192*320]        -> 1048576
#define OFF_WT   1048576     // bf16[512*2048]         -> 3145728
#define OFF_FT   3145728     // bf16[8*2048*320]       -> 13631488
#define OFF_G    13631488    // bf16[1536*2048]        -> 19922944
#define OFF_PART 19922944    // f32[4][1536][512]      -> 32505856
#define OFF_CLS  32505856    // int[2560]              -> 32516096
#define OFF_CNT  32516096    // f32[8*192]             -> 32522240

static __device__ inline unsigned short f2bf(float x) {
    unsigned int u = __builtin_bit_cast(unsigned int, x);
    u += 0x7fffu + ((u >> 16) & 1u);
    return (unsigned short)(u >> 16);
}
static __device__ inline void gl16(const void* g, void* l) {
    __builtin_amdgcn_global_load_lds(
        (__attribute__((address_space(1))) void*)(g),
        (__attribute__((address_space(3))) void*)(l), 16, 0, 0);
}

// ---------------------------------------------------------------------------
__global__ void k_cls(const int* __restrict__ obj_id, int* __restrict__ cls)
{
    int row  = blockIdx.x * 4 + (threadIdx.x >> 6);
    int lane = threadIdx.x & 63;
    if (row >= 2560) return;
    const int* p = obj_id + (size_t)row * 353;
    int last = -1;
    #pragma unroll
    for (int base = 0; base < 384; base += 64) {
        int idx = base + lane;
        int v = (idx < 353) ? p[idx] : 0;
        unsigned long long m = __ballot(v != 0);
        if (m) last = base + 63 - __clzll(m);
    }
    if (lane == 0) cls[row] = (last < 0) ? 0 : last;
}

// ---------------------------------------------------------------------------
// K1: [0,5120) feat->featT bf16 (32x32 transpose) ; [5120,6144) W->Wt ;
//     [6144,6208) ctx mean ; [6208,6248) sAT gather ; [6248,6256) cnt
__global__ __launch_bounds__(256) void k_prep(
    const float* __restrict__ W, const float* __restrict__ fm,
    const float* __restrict__ feat, const int* __restrict__ cls,
    const float* __restrict__ A,
    unsigned short* __restrict__ Wt, float* __restrict__ ctx,
    unsigned short* __restrict__ featT, unsigned short* __restrict__ sAT,
    float* __restrict__ cnt)
{
    __shared__ float t[32][33];
    __shared__ int lcls[320];
    int bx = blockIdx.x, tid = threadIdx.x;

    if (bx < 5120) {                       // feat[b][i][d] -> featT[b][d][i] bf16
        int b  = bx / 640;
        int r  = bx % 640;
        int it = r / 64, dt = r % 64;
        int rr = tid >> 3, cc = (tid & 7) * 4;
        float4 v = *(const float4*)&feat[((size_t)b * 320 + it * 32 + rr) * 2048 + dt * 32 + cc];
        t[rr][cc] = v.x; t[rr][cc+1] = v.y; t[rr][cc+2] = v.z; t[rr][cc+3] = v.w;
        __syncthreads();
        us4 o = { f2bf(t[cc][rr]), f2bf(t[cc+1][rr]), f2bf(t[cc+2][rr]), f2bf(t[cc+3][rr]) };
        *(us4*)&featT[((size_t)b * 2048 + dt * 32 + rr) * 320 + it * 32 + cc] = o;
    } else if (bx < 6144) {                // W[2048][512] -> Wt[512][2048] bf16
        int b2 = bx - 5120;
        int r0 = (b2 >> 4) * 32, c0 = (b2 & 15) * 32;
        int rr = tid >> 3, cc = (tid & 7) * 4;
        float4 v = *(const float4*)&W[(size_t)(r0 + rr) * 512 + c0 + cc];
        t[rr][cc] = v.x; t[rr][cc+1] = v.y; t[rr][cc+2] = v.z; t[rr][cc+3] = v.w;
        __syncthreads();
        us4 o = { f2bf(t[cc][rr]), f2bf(t[cc+1][rr]), f2bf(t[cc+2][rr]), f2bf(t[cc+3][rr]) };
        *(us4*)&Wt[(size_t)(c0 + rr) * 2048 + r0 + cc] = o;
    } else if (bx < 6208) {                // ctx[b][d] = mean_t fm
        int id = (bx - 6144) * 256 + tid;
        int b = id >> 11, d = id & 2047;
        const float* p = fm + (size_t)b * 32 * 2048 + d;
        float s = 0.f;
        #pragma unroll
        for (int tt = 0; tt < 32; tt++) s += p[(size_t)tt * 2048];
        ctx[id] = s * (1.0f / 32.0f);
    } else if (bx < 6248) {                // sAT gather
        int blk = bx - 6208;               // 0..39
        int b = blk / 5, i0 = (blk % 5) * 64;
        if (tid < 64) lcls[tid] = cls[b * 320 + i0 + tid];
        __syncthreads();
        #pragma unroll
        for (int q = 0; q < 6; q++) {      // 192v x 8 i8-groups
            int u = q * 256 + tid;
            int v = u >> 3, i8 = u & 7;
            us8 o = {};
            if (v < 157) {
                #pragma unroll
                for (int j = 0; j < 8; j++)
                    o[j] = f2bf(A[v * 353 + lcls[i8 * 8 + j]] * (1.0f / 32.0f));
            }
            *(us8*)&sAT[((size_t)b * 192 + v) * 320 + i0 + i8 * 8] = o;
        }
    } else {                               // cnt[b][v] = sum_i A[v,cls]/32
        int b = bx - 6248;
        for (int i = tid; i < 320; i += 256) lcls[i] = cls[b * 320 + i];
        __syncthreads();
        if (tid < 157) {
            float s = 0.f;
            for (int i = 0; i < 320; i++) s += A[tid * 353 + lcls[i]];
            cnt[b * 192 + tid] = s * (1.0f / 32.0f);
        }
    }
}

// ---------------------------------------------------------------------------
// K2: G[b][v][d] = sum_i sAT[b,v,i]*featT[b,d,i]   (K=320, BK=64, NT=5)
// tile 64v x 128d, dbuf, both operands gl16 w/ source preswizzle ch^=(row&7).
__global__ __launch_bounds__(256) void k_gemmG(
    const unsigned short* __restrict__ sAT, const unsigned short* __restrict__ featT,
    unsigned short* __restrict__ G)
{
    int bx = blockIdx.x;
    int b = bx / 48, r = bx % 48;
    int mt = r / 16, nt = r % 16;
    int m0 = mt * 64, n0 = nt * 128;

    __shared__ __align__(16) unsigned short la[2][64 * 64];
    __shared__ __align__(16) unsigned short lb[2][128 * 64];

    int tid = threadIdx.x, lane = tid & 63, w = tid >> 6;
    int wm = (w >> 1) * 32, wn = (w & 1) * 64;
    int fr = lane & 15, fk = lane >> 4;

    const unsigned short* gA[2];
    #pragma unroll
    for (int c = 0; c < 2; c++) {
        int s = c * 256 + tid, ar = s >> 3, ch = s & 7;
        gA[c] = sAT + ((size_t)b * 192 + m0 + ar) * 320 + ((ch ^ (ar & 7)) << 3);
    }
    const unsigned short* gB[4];
    #pragma unroll
    for (int c = 0; c < 4; c++) {
        int s = c * 256 + tid, er = s >> 3, ch = s & 7;
        gB[c] = featT + ((size_t)b * 2048 + n0 + er) * 320 + ((ch ^ (er & 7)) << 3);
    }

    f32x4 acc[2][4] = {};

    auto stage = [&](int buf, int kk) {
        #pragma unroll
        for (int c = 0; c < 2; c++) gl16(gA[c] + kk, &la[buf][(c * 256 + tid) * 8]);
        #pragma unroll
        for (int c = 0; c < 4; c++) gl16(gB[c] + kk, &lb[buf][(c * 256 + tid) * 8]);
    };
    auto compute = [&](int buf) {
        #pragma unroll
        for (int k2 = 0; k2 < 2; k2++) {
            short8 af[2], bf[4];
            #pragma unroll
            for (int mi = 0; mi < 2; mi++) {
                int rr = wm + mi * 16 + fr;
                af[mi] = *(const short8*)&la[buf][rr * 64 + (((k2 * 4 + fk) ^ (rr & 7)) << 3)];
            }
            #pragma unroll
            for (int ni = 0; ni < 4; ni++) {
                int rr = wn + ni * 16 + fr;
                bf[ni] = *(const short8*)&lb[buf][rr * 64 + (((k2 * 4 + fk) ^ (rr & 7)) << 3)];
            }
            #pragma unroll
            for (int mi = 0; mi < 2; mi++)
                #pragma unroll
                for (int ni = 0; ni < 4; ni++)
                    acc[mi][ni] = __builtin_amdgcn_mfma_f32_16x16x32_bf16(
                        af[mi], bf[ni], acc[mi][ni], 0, 0, 0);
        }
    };

    stage(0, 0);
    __syncthreads();
    int cur = 0;
    #pragma unroll 1
    for (int t = 0; t < 5; t++) {
        if (t < 4) stage(cur ^ 1, (t + 1) * 64);
        compute(cur);
        __syncthreads();
        cur ^= 1;
    }

    #pragma unroll
    for (int mi = 0; mi < 2; mi++) {
        int v0 = m0 + wm + mi * 16 + fk * 4;
        #pragma unroll
        for (int ni = 0; ni < 4; ni++) {
            int d = n0 + wn + ni * 16 + fr;
            #pragma unroll
            for (int rr = 0; rr < 4; rr++)
                G[((size_t)b * 192 + v0 + rr) * 2048 + d] = f2bf(acc[mi][ni][rr]);
        }
    }
}

// ---------------------------------------------------------------------------
// K3: part[ks][m][e] = sum_{d in ks-chunk} G[m,d]*Wt[e,d]   (M=1536, split-K=4)
// tile 64m x 128e, BK=64, NT=8, dbuf, both operands gl16 preswizzled.
__global__ __launch_bounds__(256) void k_gemm2(
    const unsigned short* __restrict__ G, const unsigned short* __restrict__ Wt,
    float* __restrict__ part)
{
    int bx = blockIdx.x;
    int ks = bx & 3, nt = (bx >> 2) & 3, mt = bx >> 4;     // mt 0..23
    int m0 = mt * 64, n0 = nt * 128, k0 = ks * 512;

    __shared__ __align__(16) unsigned short la[2][64 * 64];
    __shared__ __align__(16) unsigned short lb[2][128 * 64];

    int tid = threadIdx.x, lane = tid & 63, w = tid >> 6;
    int wm = (w >> 1) * 32, wn = (w & 1) * 64;
    int fr = lane & 15, fk = lane >> 4;

    const unsigned short* gA[2];
    #pragma unroll
    for (int c = 0; c < 2; c++) {
        int s = c * 256 + tid, ar = s >> 3, ch = s & 7;
        gA[c] = G + (size_t)(m0 + ar) * 2048 + k0 + ((ch ^ (ar & 7)) << 3);
    }
    const unsigned short* gB[4];
    #pragma unroll
    for (int c = 0; c < 4; c++) {
        int s = c * 256 + tid, er = s >> 3, ch = s & 7;
        gB[c] = Wt + (size_t)(n0 + er) * 2048 + k0 + ((ch ^ (er & 7)) << 3);
    }

    f32x4 acc[2][4] = {};

    auto stage = [&](int buf, int kk) {
        #pragma unroll
        for (int c = 0; c < 2; c++) gl16(gA[c] + kk, &la[buf][(c * 256 + tid) * 8]);
        #pragma unroll
        for (int c = 0; c < 4; c++) gl16(gB[c] + kk, &lb[buf][(c * 256 + tid) * 8]);
    };
    auto compute = [&](int buf) {
        #pragma unroll
        for (int k2 = 0; k2 < 2; k2++) {
            short8 af[2], bf[4];
            #pragma unroll
            for (int mi = 0; mi < 2; mi++) {
                int rr = wm + mi * 16 + fr;
                af[mi] = *(const short8*)&la[buf][rr * 64 + (((k2 * 4 + fk) ^ (rr & 7)) << 3)];
            }
            #pragma unroll
            for (int ni = 0; ni < 4; ni++) {
                int rr = wn + ni * 16 + fr;
                bf[ni] = *(const short8*)&lb[buf][rr * 64 + (((k2 * 4 + fk) ^ (rr & 7)) << 3)];
            }
            #pragma unroll
            for (int mi = 0; mi < 2; mi++)
                #pragma unroll
                for (int ni = 0; ni < 4; ni++)
                    acc[mi][ni] = __builtin_amdgcn_mfma_f32_16x16x32_bf16(
                        af[mi], bf[ni], acc[mi][ni], 0, 0, 0);
        }
    };

    stage(0, 0);
    __syncthreads();
    int cur = 0;
    #pragma unroll 1
    for (int t = 0; t < 8; t++) {
        if (t < 7) stage(cur ^ 1, (t + 1) * 64);
        compute(cur);
        __syncthreads();
        cur ^= 1;
    }

    float* P = part + (size_t)ks * 1536 * 512;
    #pragma unroll
    for (int mi = 0; mi < 2; mi++) {
        int mrow = m0 + wm + mi * 16 + fk * 4;
        #pragma unroll
        for (int ni = 0; ni < 4; ni++) {
            int e = n0 + wn + ni * 16 + fr;
            #pragma unroll
            for (int rr = 0; rr < 4; rr++)
                P[(size_t)(mrow + rr) * 512 + e] = acc[mi][ni][rr];
        }
    }
}

// ---------------------------------------------------------------------------
// K4: [0,768): out[b,v,e] = sum_ks part + cnt*bias ; [768,3280): ctx bcast
__global__ void k_fin(const float* __restrict__ part, const float* __restrict__ cnt,
                      const float* __restrict__ bias, const float* __restrict__ ctx,
                      float* __restrict__ out)
{
    if (blockIdx.x < 768) {
        int id = blockIdx.x * 256 + threadIdx.x;   // 1536*128
        int e4 = id & 127;
        int m  = id >> 7;
        int v = m % 192, b = m / 192;
        if (v >= 157) return;
        float4 s = ((const float4*)bias)[e4];
        float c = cnt[m];
        s.x *= c; s.y *= c; s.z *= c; s.w *= c;
        #pragma unroll
        for (int ks = 0; ks < 4; ks++) {
            float4 p = *(const float4*)&part[((size_t)ks * 1536 + m) * 512 + e4 * 4];
            s.x += p.x; s.y += p.y; s.z += p.z; s.w += p.w;
        }
        *(float4*)&out[((size_t)b * 157 + v) * 2560 + e4 * 4] = s;
    } else {
        int id = (blockIdx.x - 768) * 256 + threadIdx.x;   // 643072
        if (id >= 8 * 157 * 512) return;
        int q = id & 511, bv = id >> 9, b = bv / 157;
        float4 v = *(const float4*)&ctx[((size_t)b << 11) + q * 4];
        *(float4*)&out[(size_t)bv * 2560 + 512 + q * 4] = v;
    }
}

// ---------------------------------------------------------------------------
extern "C" void kernel_launch(void* const* d_in, const int* in_sizes, int n_in,
                              void* d_out, int out_size, void* d_ws, size_t ws_size,
                              hipStream_t stream)
{
    const float* feat = (const float*)d_in[0];
    const float* fm   = (const float*)d_in[1];
    const int*   obj  = (const int*)d_in[2];
    const float* W    = (const float*)d_in[3];
    const float* bias = (const float*)d_in[4];
    const float* A    = (const float*)d_in[5];
    float* out = (float*)d_out;

    char* ws = (char*)d_ws;
    float*          ctx   = (float*)(ws + OFF_CTX);
    unsigned short* sAT   = (unsigned short*)(ws + OFF_SAT);
    unsigned short* Wt    = (unsigned short*)(ws + OFF_WT);
    unsigned short* featT = (unsigned short*)(ws + OFF_FT);
    unsigned short* G     = (unsigned short*)(ws + OFF_G);
    float*          part  = (float*)(ws + OFF_PART);
    int*            cls   = (int*)(ws + OFF_CLS);
    float*          cnt   = (float*)(ws + OFF_CNT);

    k_cls  <<<640, 256, 0, stream>>>(obj, cls);
    k_prep <<<6256, 256, 0, stream>>>(W, fm, feat, cls, A, Wt, ctx, featT, sAT, cnt);
    k_gemmG<<<384, 256, 0, stream>>>(sAT, featT, G);
    k_gemm2<<<384, 256, 0, stream>>>(G, Wt, part);
    k_fin  <<<3280, 256, 0, stream>>>(part, cnt, bias, ctx, out);
}